// Round 1
// baseline (489.040 us; speedup 1.0000x reference)
//
#include <hip/hip_runtime.h>
#include <hip/hip_bf16.h>
#include <stdint.h>

// ---------------------------------------------------------------------------
// Fused MHA block: QKV proj -> attention (weights are output[1]) -> FC proj
// B=2 S=2048 E=1024 H=16 Dh=64.  All matmuls bf16 MFMA 16x16x32, fp32 accum.
// ---------------------------------------------------------------------------

typedef __attribute__((ext_vector_type(8))) short bf16x8;
typedef __attribute__((ext_vector_type(4))) short bf16x4;
typedef __attribute__((ext_vector_type(4))) float f32x4;

#define MFMA16(a, b, c) __builtin_amdgcn_mfma_f32_16x16x32_bf16(a, b, c, 0, 0, 0)

__device__ __forceinline__ short f2bf(float x) {
  uint32_t u = __builtin_bit_cast(uint32_t, x);
  u += 0x7FFFu + ((u >> 16) & 1u);   // round-to-nearest-even
  return (short)(u >> 16);
}

__device__ __forceinline__ void gload16(const void* g, void* l) {
  // async global->LDS, 16B per lane; LDS dest = wave-uniform base + lane*16
  __builtin_amdgcn_global_load_lds((const __attribute__((address_space(1))) uint32_t*)g,
                                   (__attribute__((address_space(3))) uint32_t*)l, 16, 0, 0);
}

// ------------------------------- fp32 -> bf16 ------------------------------
__global__ __launch_bounds__(256) void cvt_k(const float* __restrict__ src,
                                             short* __restrict__ dst, int n4) {
  int i = blockIdx.x * 256 + threadIdx.x;
  if (i < n4) {
    f32x4 v = *(const f32x4*)(src + (size_t)i * 4);
    bf16x4 o;
    o[0] = f2bf(v[0]); o[1] = f2bf(v[1]); o[2] = f2bf(v[2]); o[3] = f2bf(v[3]);
    *(bf16x4*)(dst + (size_t)i * 4) = o;
  }
}

// ------------------------------- GEMM (NT) ---------------------------------
// C[M][N] = A[M][K] * B[N][K]^T.  128x128 tile, BK=32, 4 waves (2x2), each
// wave 64x64 = 4x4 MFMA frags.  EPI=0: scatter into Q/K [BH][S][Dh] and
// Vt [BH][Dh][S] bf16 with bias.  EPI=1: fp32 out [M][1024] with bias.
template <int EPI>
__global__ __launch_bounds__(256) void gemm_k(
    const short* __restrict__ A, const short* __restrict__ B,
    const float* __restrict__ bq, const float* __restrict__ bk,
    const float* __restrict__ bv,
    short* __restrict__ Qb, short* __restrict__ Kb, short* __restrict__ Vt,
    float* __restrict__ Fout) {
  const int K = 1024;
  __shared__ short sA[128 * 32];
  __shared__ short sB[128 * 32];
  const int tid = threadIdx.x;
  const int w = tid >> 6, lane = tid & 63;
  const int wr = w >> 1, wc = w & 1;
  const int lrow = lane & 15, lk = (lane >> 4) * 8;
  const int tileM = blockIdx.x * 128, tileN = blockIdx.y * 128;

  f32x4 acc[4][4];
#pragma unroll
  for (int i = 0; i < 4; ++i)
#pragma unroll
    for (int j = 0; j < 4; ++j) acc[i][j] = (f32x4){0.f, 0.f, 0.f, 0.f};

  for (int k0 = 0; k0 < K; k0 += 32) {
#pragma unroll
    for (int i = 0; i < 2; ++i) {
      int u = (w * 2 + i) * 64 + lane;       // 16B unit index, 512 total
      int row = u >> 2, c8 = (u & 3) * 8;
      gload16(A + (size_t)(tileM + row) * K + k0 + c8, (short*)sA + (w * 2 + i) * 512);
      gload16(B + (size_t)(tileN + row) * K + k0 + c8, (short*)sB + (w * 2 + i) * 512);
    }
    __syncthreads();
    bf16x8 af[4], bfr[4];
#pragma unroll
    for (int mi = 0; mi < 4; ++mi)
      af[mi] = *(const bf16x8*)&sA[(wr * 64 + mi * 16 + lrow) * 32 + lk];
#pragma unroll
    for (int ni = 0; ni < 4; ++ni)
      bfr[ni] = *(const bf16x8*)&sB[(wc * 64 + ni * 16 + lrow) * 32 + lk];
#pragma unroll
    for (int mi = 0; mi < 4; ++mi)
#pragma unroll
      for (int ni = 0; ni < 4; ++ni)
        acc[mi][ni] = MFMA16(af[mi], bfr[ni], acc[mi][ni]);
    __syncthreads();
  }

  // epilogue: D frag layout col = lane&15, row = (lane>>4)*4 + r
#pragma unroll
  for (int mi = 0; mi < 4; ++mi) {
    int m0 = tileM + wr * 64 + mi * 16 + (lane >> 4) * 4;
#pragma unroll
    for (int ni = 0; ni < 4; ++ni) {
      int n = tileN + wc * 64 + ni * 16 + lrow;
      f32x4 v = acc[mi][ni];
      if (EPI == 0) {
        int which = n >> 10, e = n & 1023;
        int h = e >> 6, dh = e & 63;
        float bias = (which == 0 ? bq : which == 1 ? bk : bv)[e];
        int b = m0 >> 11, s0 = m0 & 2047;
        size_t hb = (size_t)(b * 16 + h);
        if (which == 2) {                   // V stored transposed [BH][Dh][S]
          bf16x4 pk;
#pragma unroll
          for (int r = 0; r < 4; ++r) pk[r] = f2bf(v[r] + bias);
          *(bf16x4*)&Vt[(hb * 64 + dh) * 2048 + s0] = pk;
        } else {
          short* dst = (which == 0) ? Qb : Kb;
#pragma unroll
          for (int r = 0; r < 4; ++r)
            dst[(hb * 2048 + s0 + r) * 64 + dh] = f2bf(v[r] + bias);
        }
      } else {
        float bias = bq[n];
#pragma unroll
        for (int r = 0; r < 4; ++r)
          Fout[(size_t)(m0 + r) * 1024 + n] = v[r] + bias;
      }
    }
  }
}

// ------------------------------- attention ---------------------------------
// block = 4 waves; wave w handles 16 q-rows of one (b,h).  Sweep 1: row
// sum(exp(s)) (logits ~N(0,0.33): no max subtraction needed in fp32).
// Sweep 2: recompute scores, write normalized weights fp32 to d_out, LDS
// round-trip P-tile into MFMA-A layout, accumulate PV.
__global__ __launch_bounds__(256) void attn_k(
    const short* __restrict__ Qb, const short* __restrict__ Kb,
    const short* __restrict__ Vt, float* __restrict__ Wout,
    short* __restrict__ attn) {
  __shared__ short Wlds[4][16 * 32];
  const int qt = blockIdx.x, bh = blockIdx.y;
  const int w = threadIdx.x >> 6, lane = threadIdx.x & 63;
  const int lrow = lane & 15, lk = (lane >> 4) * 8;
  const int qbase = qt * 64 + w * 16;
  const short* Qh = Qb + (size_t)bh * (2048 * 64);
  const short* Kh = Kb + (size_t)bh * (2048 * 64);
  const short* Vh = Vt + (size_t)bh * (64 * 2048);
  const float scale = 0.125f;  // 1/sqrt(64)
  const f32x4 zero = {0.f, 0.f, 0.f, 0.f};

  bf16x8 aQ0 = *(const bf16x8*)&Qh[(size_t)(qbase + lrow) * 64 + lk];
  bf16x8 aQ1 = *(const bf16x8*)&Qh[(size_t)(qbase + lrow) * 64 + 32 + lk];

  float lsum[4] = {0.f, 0.f, 0.f, 0.f};
  for (int kt = 0; kt < 128; ++kt) {
    const short* Kr = &Kh[(size_t)(kt * 16 + lrow) * 64 + lk];
    bf16x8 b0 = *(const bf16x8*)Kr;
    bf16x8 b1 = *(const bf16x8*)(Kr + 32);
    f32x4 s = MFMA16(aQ0, b0, zero);
    s = MFMA16(aQ1, b1, s);
#pragma unroll
    for (int r = 0; r < 4; ++r) {
      float e = __expf(s[r] * scale);
      e += __shfl_xor(e, 1);
      e += __shfl_xor(e, 2);
      e += __shfl_xor(e, 4);
      e += __shfl_xor(e, 8);     // all 16 lanes of the row group hold row-sum
      lsum[r] += e;
    }
  }
  float rl[4];
#pragma unroll
  for (int r = 0; r < 4; ++r) rl[r] = 1.0f / lsum[r];

  f32x4 o[4] = {zero, zero, zero, zero};
  float* Wq = Wout + ((size_t)bh * 2048 + qbase) * 2048;
  for (int kt2 = 0; kt2 < 64; ++kt2) {
#pragma unroll
    for (int half = 0; half < 2; ++half) {
      int kt = kt2 * 2 + half;
      const short* Kr = &Kh[(size_t)(kt * 16 + lrow) * 64 + lk];
      bf16x8 b0 = *(const bf16x8*)Kr;
      bf16x8 b1 = *(const bf16x8*)(Kr + 32);
      f32x4 s = MFMA16(aQ0, b0, zero);
      s = MFMA16(aQ1, b1, s);
#pragma unroll
      for (int r = 0; r < 4; ++r) {
        int qr = (lane >> 4) * 4 + r;
        float e = __expf(s[r] * scale) * rl[r];
        Wq[(size_t)qr * 2048 + kt * 16 + lrow] = e;          // weights out
        Wlds[w][qr * 32 + half * 16 + lrow] = f2bf(e);       // P-tile for PV
      }
    }
    __syncthreads();
    bf16x8 aW = *(const bf16x8*)&Wlds[w][lrow * 32 + lk];
    int k0 = kt2 * 32;
#pragma unroll
    for (int ni = 0; ni < 4; ++ni) {
      bf16x8 bv8 = *(const bf16x8*)&Vh[(size_t)(ni * 16 + lrow) * 2048 + k0 + lk];
      o[ni] = MFMA16(aW, bv8, o[ni]);
    }
    __syncthreads();
  }
  const int b = bh >> 4, h = bh & 15;
#pragma unroll
  for (int ni = 0; ni < 4; ++ni)
#pragma unroll
    for (int r = 0; r < 4; ++r)
      attn[(size_t)(b * 2048 + qbase + (lane >> 4) * 4 + r) * 1024 + h * 64 +
           ni * 16 + lrow] = f2bf(o[ni][r]);
}

// ------------------------------- launch ------------------------------------
extern "C" void kernel_launch(void* const* d_in, const int* in_sizes, int n_in,
                              void* d_out, int out_size, void* d_ws,
                              size_t ws_size, hipStream_t stream) {
  const float* x   = (const float*)d_in[0];
  const float* Wq  = (const float*)d_in[1];
  const float* bq  = (const float*)d_in[2];
  const float* Wk  = (const float*)d_in[3];
  const float* bk  = (const float*)d_in[4];
  const float* Wv  = (const float*)d_in[5];
  const float* bv  = (const float*)d_in[6];
  const float* Wfc = (const float*)d_in[7];
  const float* bfc = (const float*)d_in[8];

  float* out  = (float*)d_out;                 // [2,2048,1024]
  float* wout = out + (size_t)4194304;         // [2,16,2048,2048]

  char* ws = (char*)d_ws;
  short* xb   = (short*)(ws);                  // 8 MB  (aliased: attn reuses it)
  short* wqkv = (short*)(ws + ((size_t)8  << 20));  // 6 MB: Wq|Wk|Wv rows
  short* wfcb = (short*)(ws + ((size_t)14 << 20));  // 2 MB
  short* Qb   = (short*)(ws + ((size_t)16 << 20));  // 8 MB [BH][S][Dh]
  short* Kb   = (short*)(ws + ((size_t)24 << 20));  // 8 MB [BH][S][Dh]
  short* Vt   = (short*)(ws + ((size_t)32 << 20));  // 8 MB [BH][Dh][S]
  short* attn = xb;                            // reuse after QKV GEMM reads xb

  // fp32 -> bf16
  cvt_k<<<4096, 256, 0, stream>>>(x, xb, 1048576);
  cvt_k<<<1024, 256, 0, stream>>>(Wq, wqkv, 262144);
  cvt_k<<<1024, 256, 0, stream>>>(Wk, wqkv + 1048576, 262144);
  cvt_k<<<1024, 256, 0, stream>>>(Wv, wqkv + 2097152, 262144);
  cvt_k<<<1024, 256, 0, stream>>>(Wfc, wfcb, 262144);

  // QKV projection: [4096,3072] = xb[4096,1024] @ wqkv[3072,1024]^T
  gemm_k<0><<<dim3(32, 24), 256, 0, stream>>>(xb, wqkv, bq, bk, bv, Qb, Kb, Vt,
                                              (float*)nullptr);

  // attention: grid (S/64, B*H)
  attn_k<<<dim3(32, 32), 256, 0, stream>>>(Qb, Kb, Vt, wout, attn);

  // FC: out[4096,1024] = attn[4096,1024] @ wfcb[1024,1024]^T + bfc
  gemm_k<1><<<dim3(32, 8), 256, 0, stream>>>(attn, wfcb, bfc, nullptr, nullptr,
                                             nullptr, nullptr, nullptr, out);
}

// Round 2
// 487.945 us; speedup vs baseline: 1.0022x; 1.0022x over previous
//
#include <hip/hip_runtime.h>
#include <hip/hip_bf16.h>
#include <stdint.h>

// ---------------------------------------------------------------------------
// Fused MHA block: QKV proj -> attention (weights are output[1]) -> FC proj
// B=2 S=2048 E=1024 H=16 Dh=64.  All matmuls bf16 MFMA 16x16x32, fp32 accum.
// ---------------------------------------------------------------------------

typedef __attribute__((ext_vector_type(8))) short bf16x8;
typedef __attribute__((ext_vector_type(4))) short bf16x4;
typedef __attribute__((ext_vector_type(4))) float f32x4;

#define MFMA16(a, b, c) __builtin_amdgcn_mfma_f32_16x16x32_bf16(a, b, c, 0, 0, 0)

__device__ __forceinline__ short f2bf(float x) {
  uint32_t u = __builtin_bit_cast(uint32_t, x);
  u += 0x7FFFu + ((u >> 16) & 1u);   // round-to-nearest-even
  return (short)(u >> 16);
}

__device__ __forceinline__ uint32_t cvtpk_bf16(float lo, float hi) {
  uint32_t r;
  asm("v_cvt_pk_bf16_f32 %0, %1, %2" : "=v"(r) : "v"(lo), "v"(hi));
  return r;  // low 16 = lo, high 16 = hi
}

__device__ __forceinline__ void gload16(const void* g, void* l) {
  // async global->LDS, 16B per lane; LDS dest = wave-uniform base + lane*16
  __builtin_amdgcn_global_load_lds((const __attribute__((address_space(1))) uint32_t*)g,
                                   (__attribute__((address_space(3))) uint32_t*)l, 16, 0, 0);
}

// ------------------------------- fp32 -> bf16 ------------------------------
__global__ __launch_bounds__(256) void cvt_k(const float* __restrict__ src,
                                             short* __restrict__ dst, int n4) {
  int i = blockIdx.x * 256 + threadIdx.x;
  if (i < n4) {
    f32x4 v = *(const f32x4*)(src + (size_t)i * 4);
    bf16x4 o;
    o[0] = f2bf(v[0]); o[1] = f2bf(v[1]); o[2] = f2bf(v[2]); o[3] = f2bf(v[3]);
    *(bf16x4*)(dst + (size_t)i * 4) = o;
  }
}

// ------------------------------- GEMM (NT) ---------------------------------
// C[M][N] = A[M][K] * B[N][K]^T.  128x128 tile, BK=32, 4 waves (2x2), each
// wave 64x64 = 4x4 MFMA frags.  EPI=0: scatter into Q/K [BH][S][Dh] and
// Vt [BH][Dh][S] bf16 with bias.  EPI=1: fp32 out [M][1024] with bias.
template <int EPI>
__global__ __launch_bounds__(256) void gemm_k(
    const short* __restrict__ A, const short* __restrict__ B,
    const float* __restrict__ bq, const float* __restrict__ bk,
    const float* __restrict__ bv,
    short* __restrict__ Qb, short* __restrict__ Kb, short* __restrict__ Vt,
    float* __restrict__ Fout) {
  const int K = 1024;
  __shared__ short sA[128 * 32];
  __shared__ short sB[128 * 32];
  const int tid = threadIdx.x;
  const int w = tid >> 6, lane = tid & 63;
  const int wr = w >> 1, wc = w & 1;
  const int lrow = lane & 15, lk = (lane >> 4) * 8;
  const int tileM = blockIdx.x * 128, tileN = blockIdx.y * 128;

  f32x4 acc[4][4];
#pragma unroll
  for (int i = 0; i < 4; ++i)
#pragma unroll
    for (int j = 0; j < 4; ++j) acc[i][j] = (f32x4){0.f, 0.f, 0.f, 0.f};

  for (int k0 = 0; k0 < K; k0 += 32) {
#pragma unroll
    for (int i = 0; i < 2; ++i) {
      int u = (w * 2 + i) * 64 + lane;       // 16B unit index, 512 total
      int row = u >> 2, c8 = (u & 3) * 8;
      gload16(A + (size_t)(tileM + row) * K + k0 + c8, (short*)sA + (w * 2 + i) * 512);
      gload16(B + (size_t)(tileN + row) * K + k0 + c8, (short*)sB + (w * 2 + i) * 512);
    }
    __syncthreads();
    bf16x8 af[4], bfr[4];
#pragma unroll
    for (int mi = 0; mi < 4; ++mi)
      af[mi] = *(const bf16x8*)&sA[(wr * 64 + mi * 16 + lrow) * 32 + lk];
#pragma unroll
    for (int ni = 0; ni < 4; ++ni)
      bfr[ni] = *(const bf16x8*)&sB[(wc * 64 + ni * 16 + lrow) * 32 + lk];
#pragma unroll
    for (int mi = 0; mi < 4; ++mi)
#pragma unroll
      for (int ni = 0; ni < 4; ++ni)
        acc[mi][ni] = MFMA16(af[mi], bfr[ni], acc[mi][ni]);
    __syncthreads();
  }

  // epilogue: D frag layout col = lane&15, row = (lane>>4)*4 + r
#pragma unroll
  for (int mi = 0; mi < 4; ++mi) {
    int m0 = tileM + wr * 64 + mi * 16 + (lane >> 4) * 4;
#pragma unroll
    for (int ni = 0; ni < 4; ++ni) {
      int n = tileN + wc * 64 + ni * 16 + lrow;
      f32x4 v = acc[mi][ni];
      if (EPI == 0) {
        int which = n >> 10, e = n & 1023;
        int h = e >> 6, dh = e & 63;
        float bias = (which == 0 ? bq : which == 1 ? bk : bv)[e];
        int b = m0 >> 11, s0 = m0 & 2047;
        size_t hb = (size_t)(b * 16 + h);
        if (which == 2) {                   // V stored transposed [BH][Dh][S]
          bf16x4 pk;
#pragma unroll
          for (int r = 0; r < 4; ++r) pk[r] = f2bf(v[r] + bias);
          *(bf16x4*)&Vt[(hb * 64 + dh) * 2048 + s0] = pk;
        } else {
          short* dst = (which == 0) ? Qb : Kb;
#pragma unroll
          for (int r = 0; r < 4; ++r)
            dst[(hb * 2048 + s0 + r) * 64 + dh] = f2bf(v[r] + bias);
        }
      } else {
        float bias = bq[n];
#pragma unroll
        for (int r = 0; r < 4; ++r)
          Fout[(size_t)(m0 + r) * 1024 + n] = v[r] + bias;
      }
    }
  }
}

// ------------------------------- attention ---------------------------------
// block = 4 waves; wave w handles 16 q-rows of one (b,h).  SWAPPED operands:
// s = mfma(K, Q) -> D[k][q]: lane holds 4 consecutive k's (k = kt*16+g*4+r)
// for q-row (lane&15).  Sweep 1: row sums with only 2 shuffles total.
// Sweep 2: recompute, vectorized f32x4 weight store, packed ds_write_b64 of
// the P-tile (per-wave LDS -> NO barriers), PV accumulate.
__global__ __launch_bounds__(256) void attn_k(
    const short* __restrict__ Qb, const short* __restrict__ Kb,
    const short* __restrict__ Vt, float* __restrict__ Wout,
    short* __restrict__ attn) {
  __shared__ short Wlds[4][16 * 40];   // row stride 40 shorts = 80 B
  const int qt = blockIdx.x, bh = blockIdx.y;
  const int w = threadIdx.x >> 6, lane = threadIdx.x & 63;
  const int lrow = lane & 15, g = lane >> 4, lk = g * 8;
  const int qbase = qt * 64 + w * 16;
  const short* Qh = Qb + (size_t)bh * (2048 * 64);
  const short* Kh = Kb + (size_t)bh * (2048 * 64);
  const short* Vh = Vt + (size_t)bh * (64 * 2048);
  const float kscale = 0.125f * 1.44269504088896f;  // 1/sqrt(64) / ln(2)
  const f32x4 zero = {0.f, 0.f, 0.f, 0.f};

  bf16x8 aQ0 = *(const bf16x8*)&Qh[(size_t)(qbase + lrow) * 64 + lk];
  bf16x8 aQ1 = *(const bf16x8*)&Qh[(size_t)(qbase + lrow) * 64 + 32 + lk];

  // ---- sweep 1: row sums of exp ----
  float lsum = 0.f;
#pragma unroll 4
  for (int kt = 0; kt < 128; ++kt) {
    const short* Kr = &Kh[(size_t)(kt * 16 + lrow) * 64 + lk];
    bf16x8 k0 = *(const bf16x8*)Kr;
    bf16x8 k1 = *(const bf16x8*)(Kr + 32);
    f32x4 s = MFMA16(k0, aQ0, zero);
    s = MFMA16(k1, aQ1, s);
#pragma unroll
    for (int r = 0; r < 4; ++r) lsum += exp2f(s[r] * kscale);
  }
  lsum += __shfl_xor(lsum, 16);
  lsum += __shfl_xor(lsum, 32);   // all lanes: full row sum for q = lane&15
  const float rl = 1.0f / lsum;

  // ---- sweep 2: weights out + PV ----
  f32x4 o[4] = {zero, zero, zero, zero};
  float* Wq = Wout + ((size_t)bh * 2048 + qbase) * 2048;
  short* wl = Wlds[w];
  for (int kt2 = 0; kt2 < 64; ++kt2) {
#pragma unroll
    for (int half = 0; half < 2; ++half) {
      const int kt = kt2 * 2 + half;
      const short* Kr = &Kh[(size_t)(kt * 16 + lrow) * 64 + lk];
      bf16x8 k0 = *(const bf16x8*)Kr;
      bf16x8 k1 = *(const bf16x8*)(Kr + 32);
      f32x4 s = MFMA16(k0, aQ0, zero);
      s = MFMA16(k1, aQ1, s);
      f32x4 e;
#pragma unroll
      for (int r = 0; r < 4; ++r) e[r] = exp2f(s[r] * kscale) * rl;
      // weights: row q = lrow, cols kt*16 + g*4 .. +3  (vector store)
      *(f32x4*)&Wq[(size_t)lrow * 2048 + kt * 16 + g * 4] = e;
      // P-tile to per-wave LDS (row q, col half*16+g*4), packed bf16
      uint2 pk;
      pk.x = cvtpk_bf16(e[0], e[1]);
      pk.y = cvtpk_bf16(e[2], e[3]);
      *(uint2*)&wl[lrow * 40 + half * 16 + g * 4] = pk;
    }
    // PV: A-frag = P rows (same-wave LDS, HW-ordered; no barrier needed)
    const bf16x8 aW = *(const bf16x8*)&wl[lrow * 40 + lk];
    const int kk = kt2 * 32;
#pragma unroll
    for (int ni = 0; ni < 4; ++ni) {
      bf16x8 bv8 = *(const bf16x8*)&Vh[(size_t)(ni * 16 + lrow) * 2048 + kk + lk];
      o[ni] = MFMA16(aW, bv8, o[ni]);
    }
  }

  const int b = bh >> 4, h = bh & 15;
#pragma unroll
  for (int ni = 0; ni < 4; ++ni)
#pragma unroll
    for (int r = 0; r < 4; ++r)
      attn[(size_t)(b * 2048 + qbase + g * 4 + r) * 1024 + h * 64 +
           ni * 16 + lrow] = f2bf(o[ni][r]);
}

// ------------------------------- launch ------------------------------------
extern "C" void kernel_launch(void* const* d_in, const int* in_sizes, int n_in,
                              void* d_out, int out_size, void* d_ws,
                              size_t ws_size, hipStream_t stream) {
  const float* x   = (const float*)d_in[0];
  const float* Wq  = (const float*)d_in[1];
  const float* bq  = (const float*)d_in[2];
  const float* Wk  = (const float*)d_in[3];
  const float* bk  = (const float*)d_in[4];
  const float* Wv  = (const float*)d_in[5];
  const float* bv  = (const float*)d_in[6];
  const float* Wfc = (const float*)d_in[7];
  const float* bfc = (const float*)d_in[8];

  float* out  = (float*)d_out;                 // [2,2048,1024]
  float* wout = out + (size_t)4194304;         // [2,16,2048,2048]

  char* ws = (char*)d_ws;
  short* xb   = (short*)(ws);                  // 8 MB  (aliased: attn reuses it)
  short* wqkv = (short*)(ws + ((size_t)8  << 20));  // 6 MB: Wq|Wk|Wv rows
  short* wfcb = (short*)(ws + ((size_t)14 << 20));  // 2 MB
  short* Qb   = (short*)(ws + ((size_t)16 << 20));  // 8 MB [BH][S][Dh]
  short* Kb   = (short*)(ws + ((size_t)24 << 20));  // 8 MB [BH][S][Dh]
  short* Vt   = (short*)(ws + ((size_t)32 << 20));  // 8 MB [BH][Dh][S]
  short* attn = xb;                            // reuse after QKV GEMM reads xb

  // fp32 -> bf16
  cvt_k<<<4096, 256, 0, stream>>>(x, xb, 1048576);
  cvt_k<<<1024, 256, 0, stream>>>(Wq, wqkv, 262144);
  cvt_k<<<1024, 256, 0, stream>>>(Wk, wqkv + 1048576, 262144);
  cvt_k<<<1024, 256, 0, stream>>>(Wv, wqkv + 2097152, 262144);
  cvt_k<<<1024, 256, 0, stream>>>(Wfc, wfcb, 262144);

  // QKV projection: [4096,3072] = xb[4096,1024] @ wqkv[3072,1024]^T
  gemm_k<0><<<dim3(32, 24), 256, 0, stream>>>(xb, wqkv, bq, bk, bv, Qb, Kb, Vt,
                                              (float*)nullptr);

  // attention: grid (S/64, B*H)
  attn_k<<<dim3(32, 32), 256, 0, stream>>>(Qb, Kb, Vt, wout, attn);

  // FC: out[4096,1024] = attn[4096,1024] @ wfcb[1024,1024]^T + bfc
  gemm_k<1><<<dim3(32, 8), 256, 0, stream>>>(attn, wfcb, bfc, nullptr, nullptr,
                                             nullptr, nullptr, nullptr, out);
}

// Round 3
// 348.172 us; speedup vs baseline: 1.4046x; 1.4014x over previous
//
#include <hip/hip_runtime.h>
#include <hip/hip_bf16.h>
#include <stdint.h>

// ---------------------------------------------------------------------------
// Fused MHA block: QKV proj -> attention (weights are output[1]) -> FC proj
// B=2 S=2048 E=1024 H=16 Dh=64.  All matmuls bf16 MFMA 16x16x32, fp32 accum.
// Q/K/V are stored in MFMA-FRAGMENT-LINEAR layout by the QKV GEMM epilogue:
//   Q/K: frag[bh][tile16][h2][lane][8]  (h2 = dh half: 0-31 / 32-63)
//   V^T: frag[bh][kt2][ni][lane][8]     (ni = dh-col group of 16)
// so every attention load is base + i*1024B + lane*16B (contiguous per wave).
// ---------------------------------------------------------------------------

typedef __attribute__((ext_vector_type(8))) short bf16x8;
typedef __attribute__((ext_vector_type(4))) short bf16x4;
typedef __attribute__((ext_vector_type(4))) float f32x4;

#define MFMA16(a, b, c) __builtin_amdgcn_mfma_f32_16x16x32_bf16(a, b, c, 0, 0, 0)

__device__ __forceinline__ short f2bf(float x) {
  uint32_t u = __builtin_bit_cast(uint32_t, x);
  u += 0x7FFFu + ((u >> 16) & 1u);   // round-to-nearest-even
  return (short)(u >> 16);
}

__device__ __forceinline__ uint32_t cvtpk_bf16(float lo, float hi) {
  uint32_t r;
  asm("v_cvt_pk_bf16_f32 %0, %1, %2" : "=v"(r) : "v"(lo), "v"(hi));
  return r;  // low 16 = lo, high 16 = hi
}

__device__ __forceinline__ void gload16(const void* g, void* l) {
  __builtin_amdgcn_global_load_lds((const __attribute__((address_space(1))) uint32_t*)g,
                                   (__attribute__((address_space(3))) uint32_t*)l, 16, 0, 0);
}

// ------------------------------- fp32 -> bf16 ------------------------------
__global__ __launch_bounds__(256) void cvt_k(const float* __restrict__ src,
                                             short* __restrict__ dst, int n4) {
  int i = blockIdx.x * 256 + threadIdx.x;
  if (i < n4) {
    f32x4 v = *(const f32x4*)(src + (size_t)i * 4);
    bf16x4 o;
    o[0] = f2bf(v[0]); o[1] = f2bf(v[1]); o[2] = f2bf(v[2]); o[3] = f2bf(v[3]);
    *(bf16x4*)(dst + (size_t)i * 4) = o;
  }
}

// ------------------------------- GEMM (NT) ---------------------------------
// C[M][N] = A[M][K] * B[N][K]^T.  128x128 tile, BK=32, 4 waves (2x2), each
// wave 64x64 = 4x4 MFMA frags.  EPI=0: scatter into fragment-linear Q/K/V
// with bias.  EPI=1: fp32 out [M][1024] with bias.
template <int EPI>
__global__ __launch_bounds__(256) void gemm_k(
    const short* __restrict__ A, const short* __restrict__ B,
    const float* __restrict__ bq, const float* __restrict__ bk,
    const float* __restrict__ bv,
    short* __restrict__ Qb, short* __restrict__ Kb, short* __restrict__ Vt,
    float* __restrict__ Fout) {
  const int K = 1024;
  __shared__ short sA[128 * 32];
  __shared__ short sB[128 * 32];
  const int tid = threadIdx.x;
  const int w = tid >> 6, lane = tid & 63;
  const int wr = w >> 1, wc = w & 1;
  const int lrow = lane & 15, lk = (lane >> 4) * 8;
  const int tileM = blockIdx.x * 128, tileN = blockIdx.y * 128;

  f32x4 acc[4][4];
#pragma unroll
  for (int i = 0; i < 4; ++i)
#pragma unroll
    for (int j = 0; j < 4; ++j) acc[i][j] = (f32x4){0.f, 0.f, 0.f, 0.f};

  for (int k0 = 0; k0 < K; k0 += 32) {
#pragma unroll
    for (int i = 0; i < 2; ++i) {
      int u = (w * 2 + i) * 64 + lane;       // 16B unit index, 512 total
      int row = u >> 2, c8 = (u & 3) * 8;
      gload16(A + (size_t)(tileM + row) * K + k0 + c8, (short*)sA + (w * 2 + i) * 512);
      gload16(B + (size_t)(tileN + row) * K + k0 + c8, (short*)sB + (w * 2 + i) * 512);
    }
    __syncthreads();
    bf16x8 af[4], bfr[4];
#pragma unroll
    for (int mi = 0; mi < 4; ++mi)
      af[mi] = *(const bf16x8*)&sA[(wr * 64 + mi * 16 + lrow) * 32 + lk];
#pragma unroll
    for (int ni = 0; ni < 4; ++ni)
      bfr[ni] = *(const bf16x8*)&sB[(wc * 64 + ni * 16 + lrow) * 32 + lk];
#pragma unroll
    for (int mi = 0; mi < 4; ++mi)
#pragma unroll
      for (int ni = 0; ni < 4; ++ni)
        acc[mi][ni] = MFMA16(af[mi], bfr[ni], acc[mi][ni]);
    __syncthreads();
  }

  // epilogue: D frag layout col = lane&15, row = (lane>>4)*4 + r
#pragma unroll
  for (int mi = 0; mi < 4; ++mi) {
    int m0 = tileM + wr * 64 + mi * 16 + (lane >> 4) * 4;
#pragma unroll
    for (int ni = 0; ni < 4; ++ni) {
      int n = tileN + wc * 64 + ni * 16 + lrow;
      f32x4 v = acc[mi][ni];
      if (EPI == 0) {
        int which = n >> 10, e = n & 1023;
        int h = e >> 6, dh = e & 63;
        float bias = (which == 0 ? bq : which == 1 ? bk : bv)[e];
        int b = m0 >> 11, s0 = m0 & 2047;   // s0 aligned to 4
        size_t hb = (size_t)(b * 16 + h);
        if (which == 2) {
          // V^T element (dh, s): kt2=s>>5, gl=(s>>3)&3, ci=s&7; ni2=dh>>4, j=dh&15
          int kt2 = s0 >> 5, gl = (s0 >> 3) & 3, ni2 = dh >> 4, j = dh & 15;
          size_t base = (((hb * 64 + kt2) * 4 + ni2) * 64 + gl * 16 + j) * 8 + (s0 & 7);
          bf16x4 pk;
#pragma unroll
          for (int r = 0; r < 4; ++r) pk[r] = f2bf(v[r] + bias);
          *(bf16x4*)&Vt[base] = pk;
        } else {
          // Q/K element (s, dh): tile=s>>4, lane=(gl*16 + (s&15)), ci=dh&7
          short* dst = (which == 0) ? Qb : Kb;
          int tile = s0 >> 4, h2 = dh >> 5, gl = (dh >> 3) & 3, ci = dh & 7;
          size_t base = (((hb * 128 + tile) * 2 + h2) * 64 + gl * 16 + (s0 & 15)) * 8 + ci;
#pragma unroll
          for (int r = 0; r < 4; ++r) dst[base + r * 8] = f2bf(v[r] + bias);
        }
      } else {
        float bias = bq[n];
#pragma unroll
        for (int r = 0; r < 4; ++r)
          Fout[(size_t)(m0 + r) * 1024 + n] = v[r] + bias;
      }
    }
  }
}

// ------------------------------- attention ---------------------------------
// block = 4 waves; wave w handles 16 q-rows of one (b,h).  Swapped operands:
// s = mfma(K, Q) -> lane (g,lrow) holds k = kt*16+g*4+r for q-row lrow.
// All Q/K/V loads are fragment-linear: base + i*1024B + lane*16B.
__global__ __launch_bounds__(256) void attn_k(
    const short* __restrict__ Qb, const short* __restrict__ Kb,
    const short* __restrict__ Vt, float* __restrict__ Wout,
    short* __restrict__ attn) {
  __shared__ short Wlds[4][2][16 * 40];   // [wave][dbuf][row stride 40]
  const int qt = blockIdx.x, bh = blockIdx.y;
  const int w = threadIdx.x >> 6, lane = threadIdx.x & 63;
  const int lrow = lane & 15, g = lane >> 4;
  const int qb = qt * 4 + w;              // 16-row q-tile index within head
  const int l8 = lane * 8;
  const short* Qf = Qb + (size_t)(bh * 128 + qb) * 1024;
  const short* Kf = Kb + (size_t)bh * (128 * 1024);
  const short* Vf = Vt + (size_t)bh * (64 * 2048);
  const float kscale = 0.125f * 1.44269504088896f;  // 1/sqrt(64) / ln(2)
  const f32x4 zero = {0.f, 0.f, 0.f, 0.f};

  const bf16x8 aQ0 = *(const bf16x8*)&Qf[l8];
  const bf16x8 aQ1 = *(const bf16x8*)&Qf[512 + l8];

  // ---- sweep 1: row sums of exp2 ----
  float ls0 = 0.f, ls1 = 0.f, ls2 = 0.f, ls3 = 0.f;
#pragma unroll 8
  for (int kt = 0; kt < 128; ++kt) {
    bf16x8 k0 = *(const bf16x8*)&Kf[kt * 1024 + l8];
    bf16x8 k1 = *(const bf16x8*)&Kf[kt * 1024 + 512 + l8];
    f32x4 s = MFMA16(k0, aQ0, zero);
    s = MFMA16(k1, aQ1, s);
    ls0 += exp2f(s[0] * kscale);
    ls1 += exp2f(s[1] * kscale);
    ls2 += exp2f(s[2] * kscale);
    ls3 += exp2f(s[3] * kscale);
  }
  float lsum = (ls0 + ls1) + (ls2 + ls3);
  lsum += __shfl_xor(lsum, 16);
  lsum += __shfl_xor(lsum, 32);   // all lanes: full row-sum for q = lrow
  const float rl = 1.0f / lsum;

  // ---- sweep 2: weights out + PV ----
  f32x4 o0 = zero, o1 = zero, o2 = zero, o3 = zero;
  float* Wqp = Wout + ((size_t)bh * 2048 + qb * 16 + lrow) * 2048 + g * 4;
#pragma unroll 2
  for (int kt2 = 0; kt2 < 64; ++kt2) {
    const short* Kt = &Kf[kt2 * 2048];
    bf16x8 k00 = *(const bf16x8*)&Kt[l8];
    bf16x8 k01 = *(const bf16x8*)&Kt[512 + l8];
    bf16x8 k10 = *(const bf16x8*)&Kt[1024 + l8];
    bf16x8 k11 = *(const bf16x8*)&Kt[1536 + l8];
    const short* Vp = &Vf[kt2 * 2048];
    bf16x8 v0 = *(const bf16x8*)&Vp[l8];
    bf16x8 v1 = *(const bf16x8*)&Vp[512 + l8];
    bf16x8 v2 = *(const bf16x8*)&Vp[1024 + l8];
    bf16x8 v3 = *(const bf16x8*)&Vp[1536 + l8];

    f32x4 sa = MFMA16(k00, aQ0, zero);
    sa = MFMA16(k01, aQ1, sa);
    f32x4 sb = MFMA16(k10, aQ0, zero);
    sb = MFMA16(k11, aQ1, sb);

    f32x4 ea, eb;
#pragma unroll
    for (int r = 0; r < 4; ++r) ea[r] = exp2f(sa[r] * kscale) * rl;
#pragma unroll
    for (int r = 0; r < 4; ++r) eb[r] = exp2f(sb[r] * kscale) * rl;

    // weights: row q=lrow, cols kt2*32 + {0,16} + g*4 (vector stores)
    *(f32x4*)&Wqp[kt2 * 32] = ea;
    *(f32x4*)&Wqp[kt2 * 32 + 16] = eb;

    // P-tile to per-wave LDS (double-buffered), packed bf16
    short* wl = &Wlds[w][kt2 & 1][0];
    uint2 pa, pb;
    pa.x = cvtpk_bf16(ea[0], ea[1]);
    pa.y = cvtpk_bf16(ea[2], ea[3]);
    pb.x = cvtpk_bf16(eb[0], eb[1]);
    pb.y = cvtpk_bf16(eb[2], eb[3]);
    *(uint2*)&wl[lrow * 40 + g * 4] = pa;
    *(uint2*)&wl[lrow * 40 + 16 + g * 4] = pb;
    const bf16x8 aW = *(const bf16x8*)&wl[lrow * 40 + g * 8];

    o0 = MFMA16(aW, v0, o0);
    o1 = MFMA16(aW, v1, o1);
    o2 = MFMA16(aW, v2, o2);
    o3 = MFMA16(aW, v3, o3);
  }

  const int b = bh >> 4, h = bh & 15;
  const size_t obase = (size_t)(b * 2048 + qb * 16 + g * 4) * 1024 + h * 64 + lrow;
#pragma unroll
  for (int r = 0; r < 4; ++r) {
    attn[obase + (size_t)r * 1024 +  0] = f2bf(o0[r]);
    attn[obase + (size_t)r * 1024 + 16] = f2bf(o1[r]);
    attn[obase + (size_t)r * 1024 + 32] = f2bf(o2[r]);
    attn[obase + (size_t)r * 1024 + 48] = f2bf(o3[r]);
  }
}

// ------------------------------- launch ------------------------------------
extern "C" void kernel_launch(void* const* d_in, const int* in_sizes, int n_in,
                              void* d_out, int out_size, void* d_ws,
                              size_t ws_size, hipStream_t stream) {
  const float* x   = (const float*)d_in[0];
  const float* Wq  = (const float*)d_in[1];
  const float* bq  = (const float*)d_in[2];
  const float* Wk  = (const float*)d_in[3];
  const float* bk  = (const float*)d_in[4];
  const float* Wv  = (const float*)d_in[5];
  const float* bv  = (const float*)d_in[6];
  const float* Wfc = (const float*)d_in[7];
  const float* bfc = (const float*)d_in[8];

  float* out  = (float*)d_out;                 // [2,2048,1024]
  float* wout = out + (size_t)4194304;         // [2,16,2048,2048]

  char* ws = (char*)d_ws;
  short* xb   = (short*)(ws);                  // 8 MB  (aliased: attn reuses it)
  short* wqkv = (short*)(ws + ((size_t)8  << 20));  // 6 MB: Wq|Wk|Wv rows
  short* wfcb = (short*)(ws + ((size_t)14 << 20));  // 2 MB
  short* Qb   = (short*)(ws + ((size_t)16 << 20));  // 8 MB frag-linear
  short* Kb   = (short*)(ws + ((size_t)24 << 20));  // 8 MB frag-linear
  short* Vt   = (short*)(ws + ((size_t)32 << 20));  // 8 MB frag-linear
  short* attn = xb;                            // reuse after QKV GEMM reads xb

  // fp32 -> bf16
  cvt_k<<<4096, 256, 0, stream>>>(x, xb, 1048576);
  cvt_k<<<1024, 256, 0, stream>>>(Wq, wqkv, 262144);
  cvt_k<<<1024, 256, 0, stream>>>(Wk, wqkv + 1048576, 262144);
  cvt_k<<<1024, 256, 0, stream>>>(Wv, wqkv + 2097152, 262144);
  cvt_k<<<1024, 256, 0, stream>>>(Wfc, wfcb, 262144);

  // QKV projection: [4096,3072] = xb[4096,1024] @ wqkv[3072,1024]^T
  gemm_k<0><<<dim3(32, 24), 256, 0, stream>>>(xb, wqkv, bq, bk, bv, Qb, Kb, Vt,
                                              (float*)nullptr);

  // attention: grid (S/64, B*H)
  attn_k<<<dim3(32, 32), 256, 0, stream>>>(Qb, Kb, Vt, wout, attn);

  // FC: out[4096,1024] = attn[4096,1024] @ wfcb[1024,1024]^T + bfc
  gemm_k<1><<<dim3(32, 8), 256, 0, stream>>>(attn, wfcb, bfc, nullptr, nullptr,
                                             nullptr, nullptr, nullptr, out);
}